// Round 3
// baseline (103.347 us; speedup 1.0000x reference)
//
#include <hip/hip_runtime.h>

#define F 128

// Probe edge_index width: int64 indices < 2^31 (here < 50000) have zero high
// words at all odd int32 positions (little-endian). 16 zero odd-words => int64.
// If int32, odd words are random indices in [0,50000): P(all 16 zero) ~ (2e-5)^16.
__global__ void detect_idx64(const int* __restrict__ ei, int* __restrict__ flag) {
    if (blockIdx.x == 0 && threadIdx.x == 0) {
        int orv = 0;
#pragma unroll
        for (int k = 0; k < 16; ++k) orv |= ei[2 * k + 1];
        *flag = (orv == 0) ? 1 : 0;
    }
}

// Pass 1: per node, 10 dot products of length F against fixed weights (fp32).
// rows 0..1: W_node ; rows 2..5: W_edge[c][0:F] ; rows 6..9: W_edge[c][F:2F]
__global__ __launch_bounds__(128) void node_pass(
    const float* __restrict__ x,       // fp32 [N,F]
    const float* __restrict__ W_node,  // fp32 [2,F]
    const float* __restrict__ b_node,  // fp32 [2]
    const float* __restrict__ W_edge,  // fp32 [4,2F]
    const float* __restrict__ b_edge,  // fp32 [4]
    float2* __restrict__ node_pot,     // fp32 [N,2]  (d_out head)
    float4* __restrict__ pu,           // fp32 [N,4]  (ws)
    float4* __restrict__ pv,           // fp32 [N,4]  (ws)
    int n_nodes)
{
    __shared__ float w[10][F];   // 5 KB, read broadcast (uniform addr) -> conflict-free
    __shared__ float bias[6];
    const int t = threadIdx.x;
    for (int i = t; i < 10 * F; i += 128) {
        const int r = i >> 7, k = i & (F - 1);
        float val;
        if (r < 2)      val = W_node[r * F + k];
        else if (r < 6) val = W_edge[(r - 2) * 2 * F + k];
        else            val = W_edge[(r - 6) * 2 * F + F + k];
        w[r][k] = val;
    }
    if (t < 2)      bias[t] = b_node[t];
    else if (t < 6) bias[t] = b_edge[t - 2];
    __syncthreads();

    const int n = blockIdx.x * 128 + t;
    if (n >= n_nodes) return;

    const float4* xr = (const float4*)(x + (size_t)n * F);  // 32 x float4
    float acc[10];
#pragma unroll
    for (int r = 0; r < 10; ++r) acc[r] = 0.f;

#pragma unroll
    for (int i = 0; i < F / 4; ++i) {
        const float4 xv = xr[i];
#pragma unroll
        for (int r = 0; r < 10; ++r) {
            const float4 wv = *(const float4*)&w[r][i * 4];  // ds_read_b128, broadcast
            acc[r] += xv.x * wv.x + xv.y * wv.y + xv.z * wv.z + xv.w * wv.w;
        }
    }

    node_pot[n] = make_float2(acc[0] + bias[0], acc[1] + bias[1]);
    pu[n] = make_float4(acc[2] + bias[2], acc[3] + bias[3],
                        acc[4] + bias[4], acc[5] + bias[5]);
    pv[n] = make_float4(acc[6], acc[7], acc[8], acc[9]);
}

// Pass 2: edge_pot[e][c] = PU[u][c] + PV[v][c]; gathers hit the 1.6 MB table in L2.
__global__ __launch_bounds__(256) void edge_pass(
    const int* __restrict__ ei,
    const int* __restrict__ idx64_flag,
    const float4* __restrict__ pu,
    const float4* __restrict__ pv,
    float4* __restrict__ edge_pot,   // fp32 [E,4]
    int n_edges)
{
    const int e = blockIdx.x * 256 + threadIdx.x;
    if (e >= n_edges) return;
    const int mode = *idx64_flag;    // same addr all threads -> broadcast, uniform branch
    int u, v;
    if (mode) {  // int64 indices: stride-2 int32, low words (little-endian)
        u = ei[2 * (size_t)e];
        v = ei[2 * ((size_t)n_edges + e)];
    } else {     // int32 indices
        u = ei[e];
        v = ei[n_edges + e];
    }
    const float4 a = pu[u];
    const float4 b = pv[v];
    edge_pot[e] = make_float4(a.x + b.x, a.y + b.y, a.z + b.z, a.w + b.w);
}

extern "C" void kernel_launch(void* const* d_in, const int* in_sizes, int n_in,
                              void* d_out, int out_size, void* d_ws, size_t ws_size,
                              hipStream_t stream) {
    const float* x      = (const float*)d_in[0];
    const int*   ei     = (const int*)d_in[1];
    const float* W_node = (const float*)d_in[2];
    const float* b_node = (const float*)d_in[3];
    const float* W_edge = (const float*)d_in[4];
    const float* b_edge = (const float*)d_in[5];

    const int n_nodes = in_sizes[0] / F;   // 50000
    const int n_edges = in_sizes[1] / 2;   // 800000

    float4* pu = (float4*)d_ws;
    float4* pv = pu + n_nodes;                         // 2 x 800 KB fp32 tables
    int* idx64_flag = (int*)(pv + n_nodes);

    float* out = (float*)d_out;
    float2* node_pot = (float2*)out;                          // [N,2] fp32
    float4* edge_pot = (float4*)(out + (size_t)2 * n_nodes);  // [E,4] fp32 @ byte 400000 (16B-aligned)

    hipLaunchKernelGGL(detect_idx64, dim3(1), dim3(64), 0, stream, ei, idx64_flag);

    const int nb1 = (n_nodes + 127) / 128;
    hipLaunchKernelGGL(node_pass, dim3(nb1), dim3(128), 0, stream,
                       x, W_node, b_node, W_edge, b_edge, node_pot, pu, pv, n_nodes);

    const int nb2 = (n_edges + 255) / 256;
    hipLaunchKernelGGL(edge_pass, dim3(nb2), dim3(256), 0, stream,
                       ei, idx64_flag, pu, pv, edge_pot, n_edges);
}

// Round 4
// 97.886 us; speedup vs baseline: 1.0558x; 1.0558x over previous
//
#include <hip/hip_runtime.h>

#define F 128

// Pass 1: quad-per-node. 4 lanes per node; lane j of a quad owns float4 slices
// {iter*4 + j} of the row (floats 16*iter+4j..+3). Wave reads 16 full 64B lines
// per load instr (all bytes used). 10 dots reduced across the quad with 2
// shuffle steps. rows 0..1: W_node ; 2..5: W_edge[c][0:F] ; 6..9: W_edge[c][F:]
__global__ __launch_bounds__(256) void node_pass(
    const float* __restrict__ x,       // fp32 [N,F]
    const float* __restrict__ W_node,  // fp32 [2,F]
    const float* __restrict__ b_node,  // fp32 [2]
    const float* __restrict__ W_edge,  // fp32 [4,2F]
    const float* __restrict__ b_edge,  // fp32 [4]
    float2* __restrict__ node_pot,     // fp32 [N,2]  (d_out head)
    float4* __restrict__ pu,           // fp32 [N,4]  (ws)
    float4* __restrict__ pv,           // fp32 [N,4]  (ws)
    int n_nodes)
{
    __shared__ float w[10][F];   // 5 KB
    __shared__ float bias[6];
    const int t = threadIdx.x;
    for (int i = t; i < 10 * F; i += 256) {
        const int r = i >> 7, k = i & (F - 1);
        float val;
        if (r < 2)      val = W_node[r * F + k];
        else if (r < 6) val = W_edge[(r - 2) * 2 * F + k];
        else            val = W_edge[(r - 6) * 2 * F + F + k];
        w[r][k] = val;
    }
    if (t < 2)      bias[t] = b_node[t];
    else if (t < 6) bias[t] = b_edge[t - 2];
    __syncthreads();

    const int quad = (blockIdx.x * 256 + t) >> 2;   // node index
    const int j = t & 3;                            // lane within quad
    if (quad >= n_nodes) return;

    const float4* xr = (const float4*)(x + (size_t)quad * F);  // 32 float4/row
    float acc[10];
#pragma unroll
    for (int r = 0; r < 10; ++r) acc[r] = 0.f;

#pragma unroll
    for (int i = 0; i < 8; ++i) {
        const float4 xv = xr[i * 4 + j];
#pragma unroll
        for (int r = 0; r < 10; ++r) {
            // 4 distinct 16B addrs per wave (banks 16i+4j..+3), broadcast x16 -> conflict-free
            const float4 wv = *(const float4*)&w[r][i * 16 + j * 4];
            acc[r] += xv.x * wv.x + xv.y * wv.y + xv.z * wv.z + xv.w * wv.w;
        }
    }
    // quad reduction: after xor(1), xor(2) every lane of the quad has the full dot
#pragma unroll
    for (int r = 0; r < 10; ++r) {
        acc[r] += __shfl_xor(acc[r], 1);
        acc[r] += __shfl_xor(acc[r], 2);
    }
    if (j == 0) {
        node_pot[quad] = make_float2(acc[0] + bias[0], acc[1] + bias[1]);
        pu[quad] = make_float4(acc[2] + bias[2], acc[3] + bias[3],
                               acc[4] + bias[4], acc[5] + bias[5]);
        pv[quad] = make_float4(acc[6], acc[7], acc[8], acc[9]);
    }
}

// Pass 2: edge_pot[e][c] = PU[u][c] + PV[v][c]; gathers hit the 1.6 MB tables
// in L2/L3. Index width (int64 vs int32) detected inline from the first odd
// int32 words: constant offsets -> s_load, wave-uniform branch, no extra kernel.
__global__ __launch_bounds__(256) void edge_pass(
    const int* __restrict__ ei,
    const float4* __restrict__ pu,
    const float4* __restrict__ pv,
    float4* __restrict__ edge_pot,   // fp32 [E,4]
    int n_edges)
{
    const int e = blockIdx.x * 256 + threadIdx.x;
    if (e >= n_edges) return;
    // int64 indices < 50000 => all high (odd) words zero. int32 mode: 4 random
    // indices all zero has P ~ (2e-5)^4. Uniform across the grid.
    const bool idx64 = ((ei[1] | ei[3] | ei[5] | ei[7]) == 0);
    int u, v;
    if (idx64) {  // little-endian int64: low word at even positions
        const int2* ei64 = (const int2*)ei;
        u = ei64[(size_t)e].x;
        v = ei64[(size_t)n_edges + e].x;
    } else {
        u = ei[e];
        v = ei[n_edges + e];
    }
    const float4 a = pu[u];
    const float4 b = pv[v];
    edge_pot[e] = make_float4(a.x + b.x, a.y + b.y, a.z + b.z, a.w + b.w);
}

extern "C" void kernel_launch(void* const* d_in, const int* in_sizes, int n_in,
                              void* d_out, int out_size, void* d_ws, size_t ws_size,
                              hipStream_t stream) {
    const float* x      = (const float*)d_in[0];
    const int*   ei     = (const int*)d_in[1];
    const float* W_node = (const float*)d_in[2];
    const float* b_node = (const float*)d_in[3];
    const float* W_edge = (const float*)d_in[4];
    const float* b_edge = (const float*)d_in[5];

    const int n_nodes = in_sizes[0] / F;   // 50000
    const int n_edges = in_sizes[1] / 2;   // 800000

    float4* pu = (float4*)d_ws;
    float4* pv = pu + n_nodes;             // 2 x 800 KB fp32 tables in ws

    float* out = (float*)d_out;
    float2* node_pot = (float2*)out;                          // [N,2] fp32
    float4* edge_pot = (float4*)(out + (size_t)2 * n_nodes);  // [E,4] fp32 @ byte 400000

    const int nb1 = (n_nodes * 4 + 255) / 256;   // 4 lanes per node
    hipLaunchKernelGGL(node_pass, dim3(nb1), dim3(256), 0, stream,
                       x, W_node, b_node, W_edge, b_edge, node_pot, pu, pv, n_nodes);

    const int nb2 = (n_edges + 255) / 256;
    hipLaunchKernelGGL(edge_pass, dim3(nb2), dim3(256), 0, stream,
                       ei, pu, pv, edge_pot, n_edges);
}

// Round 6
// 97.206 us; speedup vs baseline: 1.0632x; 1.0070x over previous
//
#include <hip/hip_runtime.h>

#define F 128

typedef float vfloat4 __attribute__((ext_vector_type(4)));
typedef float vfloat2 __attribute__((ext_vector_type(2)));

// Pass 1: quad-per-node. 4 lanes per node; lane j owns float4 slices i*4+j.
// Wave reads 16 full 64B chunks per load instr. 10 dots quad-reduced via 2
// shuffles. rows 0..1: W_node ; 2..5: W_edge[c][0:F] ; 6..9: W_edge[c][F:2F]
__global__ __launch_bounds__(256) void node_pass(
    const float* __restrict__ x,       // fp32 [N,F]
    const float* __restrict__ W_node,  // fp32 [2,F]
    const float* __restrict__ b_node,  // fp32 [2]
    const float* __restrict__ W_edge,  // fp32 [4,2F]
    const float* __restrict__ b_edge,  // fp32 [4]
    float* __restrict__ node_pot,      // fp32 [N,2]  (d_out head)
    float4* __restrict__ pu,           // fp32 [N,4]  (ws)
    float4* __restrict__ pv,           // fp32 [N,4]  (ws)
    int n_nodes)
{
    __shared__ float w[10][F];   // 5 KB
    __shared__ float bias[6];
    const int t = threadIdx.x;
    for (int i = t; i < 10 * F; i += 256) {
        const int r = i >> 7, k = i & (F - 1);
        float val;
        if (r < 2)      val = W_node[r * F + k];
        else if (r < 6) val = W_edge[(r - 2) * 2 * F + k];
        else            val = W_edge[(r - 6) * 2 * F + F + k];
        w[r][k] = val;
    }
    if (t < 2)      bias[t] = b_node[t];
    else if (t < 6) bias[t] = b_edge[t - 2];
    __syncthreads();

    const int quad = (blockIdx.x * 256 + t) >> 2;   // node index
    const int j = t & 3;                            // lane within quad
    if (quad >= n_nodes) return;

    const float4* xr = (const float4*)(x + (size_t)quad * F);
    float acc[10];
#pragma unroll
    for (int r = 0; r < 10; ++r) acc[r] = 0.f;

#pragma unroll
    for (int i = 0; i < 8; ++i) {
        const float4 xv = xr[i * 4 + j];
#pragma unroll
        for (int r = 0; r < 10; ++r) {
            // 4 distinct 16B LDS addrs/wave, broadcast x16 -> conflict-free
            const float4 wv = *(const float4*)&w[r][i * 16 + j * 4];
            acc[r] += xv.x * wv.x + xv.y * wv.y + xv.z * wv.z + xv.w * wv.w;
        }
    }
#pragma unroll
    for (int r = 0; r < 10; ++r) {
        acc[r] += __shfl_xor(acc[r], 1);
        acc[r] += __shfl_xor(acc[r], 2);
    }
    if (j == 0) {
        // node_pot is write-only output: don't pollute L2 with it
        vfloat2 np2 = {acc[0] + bias[0], acc[1] + bias[1]};
        __builtin_nontemporal_store(np2, (vfloat2*)(node_pot + 2 * (size_t)quad));
        // pu/pv ARE re-read by edge_pass: normal (cacheable) stores
        pu[quad] = make_float4(acc[2] + bias[2], acc[3] + bias[3],
                               acc[4] + bias[4], acc[5] + bias[5]);
        pv[quad] = make_float4(acc[6], acc[7], acc[8], acc[9]);
    }
}

// Pass 2: edge_pot[e][c] = PU[u][c] + PV[v][c]. Streaming traffic (indices in,
// edge_pot out) is non-temporal so the 1.6 MB pu/pv gather tables stay L2-hot.
// Index width (int64 vs int32) probed inline: constant-offset loads -> uniform.
__global__ __launch_bounds__(256) void edge_pass(
    const int* __restrict__ ei,
    const float4* __restrict__ pu,
    const float4* __restrict__ pv,
    float* __restrict__ edge_pot,    // fp32 [E,4]
    int n_edges)
{
    const int e = blockIdx.x * 256 + threadIdx.x;
    if (e >= n_edges) return;
    // int64 indices < 50000 => all high (odd) int32 words zero.
    const bool idx64 = ((ei[1] | ei[3] | ei[5] | ei[7]) == 0);
    int u, v;
    if (idx64) {  // little-endian int64: low word at even int32 positions
        u = __builtin_nontemporal_load(ei + 2 * (size_t)e);
        v = __builtin_nontemporal_load(ei + 2 * ((size_t)n_edges + e));
    } else {
        u = __builtin_nontemporal_load(ei + e);
        v = __builtin_nontemporal_load(ei + (size_t)n_edges + e);
    }
    const float4 a = pu[u];
    const float4 b = pv[v];
    vfloat4 o = {a.x + b.x, a.y + b.y, a.z + b.z, a.w + b.w};
    __builtin_nontemporal_store(o, (vfloat4*)(edge_pot + 4 * (size_t)e));
}

extern "C" void kernel_launch(void* const* d_in, const int* in_sizes, int n_in,
                              void* d_out, int out_size, void* d_ws, size_t ws_size,
                              hipStream_t stream) {
    const float* x      = (const float*)d_in[0];
    const int*   ei     = (const int*)d_in[1];
    const float* W_node = (const float*)d_in[2];
    const float* b_node = (const float*)d_in[3];
    const float* W_edge = (const float*)d_in[4];
    const float* b_edge = (const float*)d_in[5];

    const int n_nodes = in_sizes[0] / F;   // 50000
    const int n_edges = in_sizes[1] / 2;   // 800000

    float4* pu = (float4*)d_ws;
    float4* pv = pu + n_nodes;             // 2 x 800 KB fp32 tables in ws

    float* out = (float*)d_out;
    float* node_pot = out;                              // [N,2] fp32
    float* edge_pot = out + (size_t)2 * n_nodes;        // [E,4] fp32 @ byte 400000 (16B-aligned)

    const int nb1 = (n_nodes * 4 + 255) / 256;   // 4 lanes per node
    hipLaunchKernelGGL(node_pass, dim3(nb1), dim3(256), 0, stream,
                       x, W_node, b_node, W_edge, b_edge, node_pot, pu, pv, n_nodes);

    const int nb2 = (n_edges + 255) / 256;
    hipLaunchKernelGGL(edge_pass, dim3(nb2), dim3(256), 0, stream,
                       ei, pu, pv, edge_pot, n_edges);
}